// Round 9
// baseline (473.020 us; speedup 1.0000x reference)
//
#include <hip/hip_runtime.h>

#define NN 4096
#define DD 128
#define BB 128
#define QQ 5
#define MAXDEG 96
#define SRCF 0x40000000
#define WP 136            // weight LDS row pitch (ushorts): 272B rows -> balanced banks

typedef __attribute__((ext_vector_type(4))) float f32x4;

__device__ __forceinline__ float dot4f(float4 a, float4 b) {
    return a.x*b.x + a.y*b.y + a.z*b.z + a.w*b.w;
}
// round-to-nearest-even f32 -> bf16
__device__ __forceinline__ unsigned short bfr(float x) {
    unsigned u = __float_as_uint(x);
    return (unsigned short)((u + 0x7fffu + ((u >> 16) & 1u)) >> 16);
}
__device__ __forceinline__ unsigned int pack2bf(float lo, float hi) {
    return ((unsigned int)bfr(hi) << 16) | (unsigned int)bfr(lo);
}
// dot of 8 packed-bf16 weights with 8 f32 operands
__device__ __forceinline__ float dot8bf(uint4 w, const float* x) {
    float a = 0.f;
    #pragma unroll
    for (int j = 0; j < 4; ++j) {
        const unsigned int pk = (&w.x)[j];
        a += __uint_as_float(pk << 16) * x[2*j];
        a += __uint_as_float(pk & 0xffff0000u) * x[2*j+1];
    }
    return a;
}

// ---------------- neighbor-list precompute (parallel) ----------------
__global__ void nbr_kernel(const int* __restrict__ u, const int* __restrict__ v,
                           const float* __restrict__ A, const float* __restrict__ S,
                           int* __restrict__ nbr_cnt, int2* __restrict__ nbr_pack)
{
    __shared__ int   lcnt[257];
    __shared__ int   sidx[MAXDEG];
    __shared__ float sq[MAXDEG];
    __shared__ float ssum;
    __shared__ int   stot;

    const int p    = blockIdx.x;
    const int i    = p >> 1;
    const int side = p & 1;
    const int other = (side == 0) ? v[i] : u[i];
    const float* Arow = A + (size_t)other * NN;
    const float* Srow = S + (size_t)other * NN;
    const int tid = threadIdx.x;

    const int base = tid * 16;
    int c0 = 0;
    for (int j = 0; j < 16; ++j) c0 += (Arow[base + j] > 0.0f) ? 1 : 0;
    lcnt[tid] = c0;
    __syncthreads();
    if (tid == 0) {
        int s = 0;
        for (int k = 0; k < 256; ++k) { int c = lcnt[k]; lcnt[k] = s; s += c; }
        stot = s;
    }
    __syncthreads();
    int off = lcnt[tid];
    for (int j = 0; j < 16; ++j) {
        if (Arow[base + j] > 0.0f) {
            if (off < MAXDEG) sidx[off] = base + j;
            ++off;
        }
    }
    __syncthreads();
    int cnt = stot; if (cnt > MAXDEG) cnt = MAXDEG;
    for (int jj = tid; jj < cnt; jj += 256) sq[jj] = expf(Srow[sidx[jj]]);
    __syncthreads();
    if (tid == 0) {
        float s = 0.0f;
        for (int jj = 0; jj < cnt; ++jj) s += sq[jj];
        ssum = s + 1e-7f;
    }
    __syncthreads();
    for (int jj = tid; jj < cnt; jj += 256) {
        int2 pk;
        pk.x = sidx[jj];
        pk.y = __float_as_int(sq[jj] / ssum);
        nbr_pack[p * MAXDEG + jj] = pk;
    }
    if (tid == 0) nbr_cnt[p] = cnt;
}

// ---------------- Whz0[n][d] = z0[n].Wh[d] + bh[d] (parallel) ----------------
__global__ __launch_bounds__(512) void whz_init(
    const float* __restrict__ z0, const float* __restrict__ Wh, const float* __restrict__ bh,
    float* __restrict__ Whz0)
{
    const int t   = threadIdx.x;
    const int rep = t & 7;
    const int d0  = t >> 3;
    float4 wh0[4], wh1[4];
    #pragma unroll
    for (int m = 0; m < 4; ++m) {
        wh0[m] = *(const float4*)(Wh + (size_t)d0*DD + rep*16 + m*4);
        wh1[m] = *(const float4*)(Wh + (size_t)(d0+64)*DD + rep*16 + m*4);
    }
    const float bh0 = bh[d0], bh1 = bh[d0+64];
    const int r0 = blockIdx.x * 16;
    for (int r = r0; r < r0 + 16; ++r) {
        const float* zr = z0 + (size_t)r*DD + rep*16;
        float a0 = 0.f, a1 = 0.f;
        #pragma unroll
        for (int m = 0; m < 4; ++m) {
            float4 zz = *(const float4*)(zr + m*4);
            a0 += dot4f(zz, wh0[m]);
            a1 += dot4f(zz, wh1[m]);
        }
        a0 += __shfl_xor(a0,1); a0 += __shfl_xor(a0,2); a0 += __shfl_xor(a0,4);
        a1 += __shfl_xor(a1,1); a1 += __shfl_xor(a1,2); a1 += __shfl_xor(a1,4);
        if (rep == 0) {
            Whz0[(size_t)r*DD + d0]    = a0 + bh0;
            Whz0[(size_t)r*DD + d0+64] = a1 + bh1;
        }
    }
}

// ---------------- last-update sources for u,v,neg rows (parallel) ----------------
__global__ void src_kernel(const int* __restrict__ u, const int* __restrict__ v,
                           const int* __restrict__ neg,
                           int* __restrict__ zsrc, int* __restrict__ negsrc)
{
    const int i = blockIdx.x;
    const int k = threadIdx.x;
    if (k >= 2 + 2*QQ) return;
    const int n = (k == 0) ? u[i] : (k == 1) ? v[i] : neg[i*2*QQ + (k-2)];
    int s = n;
    for (int j = i-1; j >= 0; --j) {
        if (v[j] == n) { s = SRCF | (j*2 + 1); break; }
        if (u[j] == n) { s = SRCF | (j*2 + 0); break; }
    }
    if (k < 2) zsrc[i*2 + k] = s;
    else       negsrc[i*2*QQ + (k-2)] = s;
}

// ---------------- static-max + correction lists per (i,side) (parallel) ----------------
__global__ void prep_kernel(const int* __restrict__ u, const int* __restrict__ v,
                            const int* __restrict__ nbr_cnt, const int2* __restrict__ nbr_pack,
                            const float* __restrict__ Whz0,
                            float* __restrict__ maxpre, int* __restrict__ ncorr,
                            int2* __restrict__ corr_pack)
{
    __shared__ int   su[BB], sv[BB];
    __shared__ int   sidx[MAXDEG];
    __shared__ float sq[MAXDEG];
    __shared__ unsigned char cflag[MAXDEG];
    __shared__ int ccnt;

    const int p   = blockIdx.x;
    const int i   = p >> 1;
    const int tid = threadIdx.x;
    if (tid < BB) { su[tid] = u[tid]; sv[tid] = v[tid]; }
    if (tid == 0) ccnt = 0;
    const int cnt = nbr_cnt[p];
    for (int jj = tid; jj < cnt; jj += 128) {
        int2 pk = nbr_pack[p*MAXDEG + jj];
        sidx[jj] = pk.x; sq[jj] = __int_as_float(pk.y);
    }
    __syncthreads();
    for (int jj = tid; jj < cnt; jj += 128) {
        const int r = sidx[jj];
        int fs = -1;
        for (int j = i-1; j >= 0; --j) {
            if (sv[j] == r) { fs = j*2 + 1; break; }
            if (su[j] == r) { fs = j*2 + 0; break; }
        }
        if (fs >= 0) {
            const int pos = atomicAdd(&ccnt, 1);   // order-free (folded with commutative max)
            int2 cp; cp.x = fs; cp.y = __float_as_int(sq[jj]);
            corr_pack[p*MAXDEG + pos] = cp;
            cflag[jj] = 1;
        } else cflag[jj] = 0;
    }
    __syncthreads();
    const int d = tid;
    float m = -3.0e38f;
    for (int jj = 0; jj < cnt; ++jj)
        if (!cflag[jj]) m = fmaxf(m, sq[jj] * Whz0[(size_t)sidx[jj]*DD + d]);
    maxpre[(size_t)p*DD + d] = m;
    if (tid == 0) ncorr[p] = ccnt;
}

// ---------------- sequential scan: 1 block, 1024 threads ----------------
// Wst/Wrc: bf16 in LDS (pitch WP, bank-balanced); Wh: packed bf16 in 8 VGPRs;
// whzlog: bf16 in LDS. No per-step global weight traffic -> r5-r8's 6500cy/step gone.
// coords: rep = t&7 (k-slice of 16), d = (t>>3)&127; P0 roles by wave (0/8 h, 1/9 z, 2 tdi)
__attribute__((amdgpu_waves_per_eu(4, 4)))
__global__ __launch_bounds__(1024) void scan_kernel(
    const float* __restrict__ z0, const float* __restrict__ time_diff,
    const int* __restrict__ nbr_cnt, const int* __restrict__ ncorr,
    const int2* __restrict__ corr_pack,
    const float* __restrict__ maxpre, const int* __restrict__ zsrc,
    const float* __restrict__ Wh,  const float* __restrict__ bh,
    const float* __restrict__ Wst, const float* __restrict__ bst,
    const float* __restrict__ Wrc, const float* __restrict__ brc,
    const float* __restrict__ Wt,  const float* __restrict__ bt,
    float* __restrict__ zlog)
{
    __shared__ unsigned short wpk_s[2][128*WP];          // Wst,Wrc bf16: 69,632 B
    __shared__ unsigned short whz_s[2*BB*DD];            // whzlog bf16: 65,536 B
    __shared__ __align__(16) float h_s[2][DD];
    __shared__ __align__(16) float zu_s[DD], zv_s[DD];
    __shared__ __align__(16) float zupd_s[2][DD];
    __shared__ float tdi_s[8];
    __shared__ int   cnt_s[2*BB], ncorr_s[2*BB], zsrc_s[2*BB];

    const int t   = threadIdx.x;
    const int wv  = t >> 6;
    const int ln  = t & 63;
    const int rep = t & 7;
    const int d   = (t >> 3) & 127;

    // ---- persistent: Wh slice as packed bf16 (8 VGPRs) + wt + biases ----
    uint4 whpa, whpb;
    {
        const float* p = Wh + (size_t)d*DD + rep*16;
        unsigned int* q = &whpa.x;
        #pragma unroll
        for (int j = 0; j < 4; ++j) q[j] = pack2bf(p[2*j], p[2*j+1]);
        q = &whpb.x; p += 8;
        #pragma unroll
        for (int j = 0; j < 4; ++j) q[j] = pack2bf(p[2*j], p[2*j+1]);
    }
    const f32x4 wt = *(const f32x4*)(Wt + (size_t)d*4);
    const float bh_d = bh[d];
    const float bs_d = bst[d] + brc[d] + bt[d];

    // ---- one-time fills: metadata + weight LDS (bf16, padded pitch) ----
    if (t < 256)       { cnt_s[t] = nbr_cnt[t]; ncorr_s[t] = ncorr[t]; }
    else if (t < 512)  { zsrc_s[t-256] = zsrc[t-256]; }
    for (int e = t; e < 2*128*64; e += 1024) {           // dword-pairs
        const int m  = e >> 13;
        const int r  = (e >> 6) & 127;
        const int k2 = e & 63;
        const float* W = m ? Wrc : Wst;
        const float lo = W[r*128 + k2*2], hi = W[r*128 + k2*2 + 1];
        *(unsigned int*)&wpk_s[m][r*WP + k2*2] = pack2bf(lo, hi);
    }
    __syncthreads();

    // ---- software-pipelined loads: maxpre (waves 0/8), zu/zv (waves 1/9) ----
    float2 mnext = make_float2(0.f, 0.f);
    float2 znext = make_float2(0.f, 0.f);
    if (wv == 0 || wv == 8) {
        const int side = wv >> 3;
        mnext = *(const float2*)&maxpre[(size_t)side*DD + ln*2];
    } else if (wv == 1 || wv == 9) {
        const int r2 = wv >> 3;
        const int s = zsrc_s[r2];                         // step 0: always a z0 row
        const float* src = (s & SRCF) ? (zlog + (size_t)(s & 0xFFFF)*DD)
                                      : (z0   + (size_t)s*DD);
        znext = *(const float2*)&src[ln*2];
    }

    const int woff = d*WP + rep*16;                       // this thread's weight slice

    for (int i = 0; i < BB; ++i) {
        // weight slices: static LDS, no B1 dependence -> issue early, reuse across r2
        const uint4 wsa = *(const uint4*)&wpk_s[0][woff];
        const uint4 wsb = *(const uint4*)&wpk_s[0][woff + 8];
        const uint4 wra = *(const uint4*)&wpk_s[1][woff];
        const uint4 wrb = *(const uint4*)&wpk_s[1][woff + 8];

        // ---- P0: h gather (maxpre + LDS bf16 corrections); pipelined zu/zv; tdi ----
        if (wv == 0 || wv == 8) {
            const int side = wv >> 3;
            const int p = i*2 + side;
            float2 m = mnext;
            const int pn = ((i+1 < BB) ? (i+1) : i)*2 + side;
            mnext = *(const float2*)&maxpre[(size_t)pn*DD + ln*2];
            const int nc = ncorr_s[p];
            for (int c = 0; c < nc; ++c) {
                const int2 cp = corr_pack[p*MAXDEG + c];
                const float qc = __int_as_float(cp.y);
                const unsigned int pk = *(const unsigned int*)&whz_s[cp.x*DD + ln*2];
                m.x = fmaxf(m.x, qc * __uint_as_float(pk << 16));
                m.y = fmaxf(m.y, qc * __uint_as_float(pk & 0xffff0000u));
            }
            if (cnt_s[p] > 0) {
                h_s[side][ln*2]   = 1.0f/(1.0f + expf(-m.x));
                h_s[side][ln*2+1] = 1.0f/(1.0f + expf(-m.y));
            } else {
                h_s[side][ln*2] = 0.0f; h_s[side][ln*2+1] = 0.0f;
            }
        } else if (wv == 1 || wv == 9) {
            const int r2 = wv >> 3;
            float* dst = r2 ? zv_s : zu_s;
            *(float2*)&dst[ln*2] = znext;                 // prefetched last step
        } else if (wv == 2 && ln < 8) {
            const float sd[4] = {50.f, 7.f, 15.f, 15.f};
            tdi_s[ln] = time_diff[i*8 + ln] / sd[ln & 3];
        }
        __syncthreads();   // B1

        // ---- P1: z_upd (weights from LDS-resident bf16; operands broadcast) ----
        #pragma unroll
        for (int r2 = 0; r2 < 2; ++r2) {
            const float* hp = h_s[r2] + rep*16;
            const float* zp = (r2 ? zv_s : zu_s) + rep*16;
            float a = dot8bf(wsa, hp) + dot8bf(wsb, hp + 8)
                    + dot8bf(wra, zp) + dot8bf(wrb, zp + 8);
            a += __shfl_xor(a,1); a += __shfl_xor(a,2); a += __shfl_xor(a,4);
            if (rep == 0) {
                const float tdr = tdi_s[r2*4+0]*wt[0] + tdi_s[r2*4+1]*wt[1]
                                + tdi_s[r2*4+2]*wt[2] + tdi_s[r2*4+3]*wt[3];
                zupd_s[r2][d] = 1.0f/(1.0f + expf(-(a + bs_d + tdr)));
            }
        }
        __syncthreads();   // B2

        // ---- P2a: prefetch next step's zu/zv ----
        if (wv == 1 || wv == 9) {
            const int r2 = wv >> 3;
            const int inx = (i+1 < BB) ? (i+1) : i;
            const int s = zsrc_s[inx*2 + r2];
            if (s & SRCF) {
                const int row = s & 0xFFFF;
                if ((row >> 1) == i) znext = *(const float2*)&zupd_s[row & 1][ln*2];
                else                 znext = *(const float2*)&zlog[(size_t)row*DD + ln*2];
            } else {
                znext = *(const float2*)&z0[(size_t)s*DD + ln*2];
            }
        }
        // ---- P2b: Whz rows of the two updates -> whz_s (bf16) + zlog (global) ----
        #pragma unroll
        for (int r2 = 0; r2 < 2; ++r2) {
            const float* zp = zupd_s[r2] + rep*16;
            float a = dot8bf(whpa, zp) + dot8bf(whpb, zp + 8);
            a += __shfl_xor(a,1); a += __shfl_xor(a,2); a += __shfl_xor(a,4);
            if (rep == 0) {
                const int row = i*2 + r2;
                whz_s[row*DD + d]        = bfr(a + bh_d);
                zlog[(size_t)row*DD + d] = zupd_s[r2][d];
            }
        }
        __threadfence_block();   // zlog global stores visible to later-step gathers
        __syncthreads();   // B3 (orders whz_s ds_writes for next P0)
    }
}

// ---------------- intensity epilogue (parallel, reads via src indices) ----------------
__global__ void lam_kernel(const float* __restrict__ z0, const float* __restrict__ zlog,
                           const int* __restrict__ zsrc, const int* __restrict__ negsrc,
                           const int* __restrict__ et,
                           const float* __restrict__ w0, const float* __restrict__ b0,
                           const float* __restrict__ w1, const float* __restrict__ b1,
                           const float* __restrict__ psi,
                           float* __restrict__ out)
{
    const int b   = blockIdx.x;
    const int i   = b / 11;
    const int col = b % 11;
    const int l   = threadIdx.x;

    auto rp = [&](int s) -> const float* {
        return (s & SRCF) ? (zlog + (size_t)(s & 0xFFFF)*DD) : (z0 + (size_t)s*DD);
    };
    const float* xu;
    const float* xv;
    if (col == 0) { xu = rp(zsrc[i*2]); xv = rp(zsrc[i*2+1]); }
    else {
        const int k = col - 1;
        xu = (k < QQ) ? rp(zsrc[i*2])            : rp(negsrc[i*2*QQ + k]);
        xv = (k < QQ) ? rp(negsrc[i*2*QQ + k])   : rp(zsrc[i*2+1]);
    }
    float g0 = xu[l]*w0[l] + xu[l+64]*w0[l+64] + xv[l]*w0[DD+l] + xv[l+64]*w0[DD+l+64];
    float g1 = xu[l]*w1[l] + xu[l+64]*w1[l+64] + xv[l]*w1[DD+l] + xv[l+64]*w1[DD+l+64];
    #pragma unroll
    for (int s = 32; s >= 1; s >>= 1) { g0 += __shfl_xor(g0, s); g1 += __shfl_xor(g1, s); }
    if (l == 0) {
        g0 += b0[0]; g1 += b1[0];
        const float p0 = psi[0], p1 = psi[1];
        float r;
        if (col == 0) {
            const int e = et[i];
            const float g = e ? g1 : g0;
            const float p = e ? p1 : p0;
            const float y = g / (p + 1e-7f);
            r = p * (fmaxf(y, 0.f) + log1pf(expf(-fabsf(y))));
        } else {
            const float y0 = g0 / (p0 + 1e-7f);
            const float y1 = g1 / (p1 + 1e-7f);
            r = p0 * (fmaxf(y0, 0.f) + log1pf(expf(-fabsf(y0))))
              + p1 * (fmaxf(y1, 0.f) + log1pf(expf(-fabsf(y1))));
        }
        out[i*11 + col] = r;
    }
}

extern "C" void kernel_launch(void* const* d_in, const int* in_sizes, int n_in,
                              void* d_out, int out_size, void* d_ws, size_t ws_size,
                              hipStream_t stream)
{
    const int*   u   = (const int*)d_in[0];
    const int*   v   = (const int*)d_in[1];
    const int*   et  = (const int*)d_in[2];
    const float* td  = (const float*)d_in[3];
    const int*   neg = (const int*)d_in[4];
    const float* z0  = (const float*)d_in[5];
    const float* A   = (const float*)d_in[6];
    const float* S   = (const float*)d_in[7];
    const float* w0  = (const float*)d_in[8];
    const float* b0  = (const float*)d_in[9];
    const float* w1  = (const float*)d_in[10];
    const float* b1  = (const float*)d_in[11];
    const float* psi = (const float*)d_in[12];
    const float* Wh  = (const float*)d_in[13];
    const float* bh  = (const float*)d_in[14];
    const float* Wst = (const float*)d_in[15];
    const float* bst = (const float*)d_in[16];
    const float* Wrc = (const float*)d_in[17];
    const float* brc = (const float*)d_in[18];
    const float* Wt  = (const float*)d_in[19];
    const float* bt  = (const float*)d_in[20];

    char* ws = (char*)d_ws;
    size_t off = 0;
    auto alloc = [&](size_t bytes) {
        void* p = ws + off;
        off = (off + bytes + 255) & ~(size_t)255;
        return p;
    };
    float* Whz0   = (float*)alloc((size_t)NN*DD*sizeof(float));
    float* maxpre = (float*)alloc((size_t)2*BB*DD*sizeof(float));
    float* zlog   = (float*)alloc((size_t)2*BB*DD*sizeof(float));
    int*   ncnt   = (int*)alloc((size_t)2*BB*sizeof(int));
    int*   ncorr  = (int*)alloc((size_t)2*BB*sizeof(int));
    int2*  cpk    = (int2*)alloc((size_t)2*BB*MAXDEG*sizeof(int2));
    int*   zsrc   = (int*)alloc((size_t)2*BB*sizeof(int));
    int*   negsrc = (int*)alloc((size_t)BB*2*QQ*sizeof(int));
    int2*  npk    = (int2*)alloc((size_t)2*BB*MAXDEG*sizeof(int2));

    whz_init<<<NN/16, 512, 0, stream>>>(z0, Wh, bh, Whz0);
    nbr_kernel<<<2*BB, 256, 0, stream>>>(u, v, A, S, ncnt, npk);
    src_kernel<<<BB, 64, 0, stream>>>(u, v, neg, zsrc, negsrc);
    prep_kernel<<<2*BB, 128, 0, stream>>>(u, v, ncnt, npk, Whz0, maxpre, ncorr, cpk);
    scan_kernel<<<1, 1024, 0, stream>>>(z0, td, ncnt, ncorr, cpk, maxpre, zsrc,
                                        Wh, bh, Wst, bst, Wrc, brc, Wt, bt, zlog);
    lam_kernel<<<BB*(1 + 2*QQ), 64, 0, stream>>>(z0, zlog, zsrc, negsrc, et,
                                                 w0, b0, w1, b1, psi, (float*)d_out);
}

// Round 10
// 450.583 us; speedup vs baseline: 1.0498x; 1.0498x over previous
//
#include <hip/hip_runtime.h>

#define NN 4096
#define DD 128
#define BB 128
#define QQ 5
#define MAXDEG 96
#define SRCF 0x40000000

typedef __attribute__((ext_vector_type(4))) float f32x4;

__device__ __forceinline__ float dot4v(f32x4 a, f32x4 b) {
    return a[0]*b[0] + a[1]*b[1] + a[2]*b[2] + a[3]*b[3];
}
__device__ __forceinline__ float dot4f(float4 a, float4 b) {
    return a.x*b.x + a.y*b.y + a.z*b.z + a.w*b.w;
}

// ---------------- neighbor-list precompute (parallel) ----------------
__global__ void nbr_kernel(const int* __restrict__ u, const int* __restrict__ v,
                           const float* __restrict__ A, const float* __restrict__ S,
                           int* __restrict__ nbr_cnt, int2* __restrict__ nbr_pack)
{
    __shared__ int   lcnt[257];
    __shared__ int   sidx[MAXDEG];
    __shared__ float sq[MAXDEG];
    __shared__ float ssum;
    __shared__ int   stot;

    const int p    = blockIdx.x;
    const int i    = p >> 1;
    const int side = p & 1;
    const int other = (side == 0) ? v[i] : u[i];   // side0 = agg(v), side1 = agg(u)
    const float* Arow = A + (size_t)other * NN;
    const float* Srow = S + (size_t)other * NN;
    const int tid = threadIdx.x;

    const int base = tid * 16;
    int c0 = 0;
    for (int j = 0; j < 16; ++j) c0 += (Arow[base + j] > 0.0f) ? 1 : 0;
    lcnt[tid] = c0;
    __syncthreads();
    if (tid == 0) {
        int s = 0;
        for (int k = 0; k < 256; ++k) { int c = lcnt[k]; lcnt[k] = s; s += c; }
        stot = s;
    }
    __syncthreads();
    int off = lcnt[tid];
    for (int j = 0; j < 16; ++j) {
        if (Arow[base + j] > 0.0f) {
            if (off < MAXDEG) sidx[off] = base + j;
            ++off;
        }
    }
    __syncthreads();
    int cnt = stot; if (cnt > MAXDEG) cnt = MAXDEG;
    for (int jj = tid; jj < cnt; jj += 256) sq[jj] = expf(Srow[sidx[jj]]);
    __syncthreads();
    if (tid == 0) {
        float s = 0.0f;
        for (int jj = 0; jj < cnt; ++jj) s += sq[jj];
        ssum = s + 1e-7f;
    }
    __syncthreads();
    for (int jj = tid; jj < cnt; jj += 256) {
        int2 pk;
        pk.x = sidx[jj];
        pk.y = __float_as_int(sq[jj] / ssum);
        nbr_pack[p * MAXDEG + jj] = pk;
    }
    if (tid == 0) nbr_cnt[p] = cnt;
}

// ---------------- Whz0[n][d] = z0[n].Wh[d] + bh[d] (parallel) ----------------
__global__ __launch_bounds__(512) void whz_init(
    const float* __restrict__ z0, const float* __restrict__ Wh, const float* __restrict__ bh,
    float* __restrict__ Whz0)
{
    const int t   = threadIdx.x;
    const int rep = t & 7;
    const int d0  = t >> 3;
    float4 wh0[4], wh1[4];
    #pragma unroll
    for (int m = 0; m < 4; ++m) {
        wh0[m] = *(const float4*)(Wh + (size_t)d0*DD + rep*16 + m*4);
        wh1[m] = *(const float4*)(Wh + (size_t)(d0+64)*DD + rep*16 + m*4);
    }
    const float bh0 = bh[d0], bh1 = bh[d0+64];
    const int r0 = blockIdx.x * 16;
    for (int r = r0; r < r0 + 16; ++r) {
        const float* zr = z0 + (size_t)r*DD + rep*16;
        float a0 = 0.f, a1 = 0.f;
        #pragma unroll
        for (int m = 0; m < 4; ++m) {
            float4 zz = *(const float4*)(zr + m*4);
            a0 += dot4f(zz, wh0[m]);
            a1 += dot4f(zz, wh1[m]);
        }
        a0 += __shfl_xor(a0,1); a0 += __shfl_xor(a0,2); a0 += __shfl_xor(a0,4);
        a1 += __shfl_xor(a1,1); a1 += __shfl_xor(a1,2); a1 += __shfl_xor(a1,4);
        if (rep == 0) {
            Whz0[(size_t)r*DD + d0]    = a0 + bh0;
            Whz0[(size_t)r*DD + d0+64] = a1 + bh1;
        }
    }
}

// ---------------- last-update sources for u,v,neg rows (parallel) ----------------
__global__ void src_kernel(const int* __restrict__ u, const int* __restrict__ v,
                           const int* __restrict__ neg,
                           int* __restrict__ zsrc, int* __restrict__ negsrc)
{
    const int i = blockIdx.x;
    const int k = threadIdx.x;
    if (k >= 2 + 2*QQ) return;
    const int n = (k == 0) ? u[i] : (k == 1) ? v[i] : neg[i*2*QQ + (k-2)];
    int s = n;
    for (int j = i-1; j >= 0; --j) {
        if (v[j] == n) { s = SRCF | (j*2 + 1); break; }
        if (u[j] == n) { s = SRCF | (j*2 + 0); break; }
    }
    if (k < 2) zsrc[i*2 + k] = s;
    else       negsrc[i*2*QQ + (k-2)] = s;
}

// ---------------- static-max + correction lists per (i,side) (parallel) ----------------
__global__ void prep_kernel(const int* __restrict__ u, const int* __restrict__ v,
                            const int* __restrict__ nbr_cnt, const int2* __restrict__ nbr_pack,
                            const float* __restrict__ Whz0,
                            float* __restrict__ maxpre, int* __restrict__ ncorr,
                            int2* __restrict__ corr_pack)
{
    __shared__ int   su[BB], sv[BB];
    __shared__ int   sidx[MAXDEG];
    __shared__ float sq[MAXDEG];
    __shared__ unsigned char cflag[MAXDEG];
    __shared__ int ccnt;

    const int p   = blockIdx.x;
    const int i   = p >> 1;
    const int tid = threadIdx.x;
    if (tid < BB) { su[tid] = u[tid]; sv[tid] = v[tid]; }
    if (tid == 0) ccnt = 0;
    const int cnt = nbr_cnt[p];
    for (int jj = tid; jj < cnt; jj += 128) {
        int2 pk = nbr_pack[p*MAXDEG + jj];
        sidx[jj] = pk.x; sq[jj] = __int_as_float(pk.y);
    }
    __syncthreads();
    for (int jj = tid; jj < cnt; jj += 128) {
        const int r = sidx[jj];
        int fs = -1;
        for (int j = i-1; j >= 0; --j) {
            if (sv[j] == r) { fs = j*2 + 1; break; }
            if (su[j] == r) { fs = j*2 + 0; break; }
        }
        if (fs >= 0) {
            const int pos = atomicAdd(&ccnt, 1);   // order-free (folded with commutative max)
            int2 cp; cp.x = fs; cp.y = __float_as_int(sq[jj]);
            corr_pack[p*MAXDEG + pos] = cp;
            cflag[jj] = 1;
        } else cflag[jj] = 0;
    }
    __syncthreads();
    const int d = tid;
    float m = -3.0e38f;
    for (int jj = 0; jj < cnt; ++jj)
        if (!cflag[jj]) m = fmaxf(m, sq[jj] * Whz0[(size_t)sidx[jj]*DD + d]);
    maxpre[(size_t)p*DD + d] = m;
    if (tid == 0) ncorr[p] = ccnt;
}

// ---------------- sequential scan: 1 block, 1024 threads, Whzlog in LDS ----------------
// coords: rep = t&7 (k-slice of 16), d = (t>>3)&127 (single output dim)
// P0 roles by wave wv = t>>6: wv0/8 = h sides, wv1/9 = zu/zv (pipelined), wv2 = tdi
// amdgpu_waves_per_eu(4,4): max=4 forbids the RA's default 8-wave/64-VGPR target ->
// budget 128 VGPR -> the 54 persistent weight regs stay resident (kills r5-r9's
// ~400KB/step L2 remat stream, the dominant per-step cost)
__attribute__((amdgpu_waves_per_eu(4, 4)))
__global__ __launch_bounds__(1024) void scan_kernel(
    const float* __restrict__ z0, const float* __restrict__ time_diff,
    const int* __restrict__ nbr_cnt, const int* __restrict__ ncorr,
    const int2* __restrict__ corr_pack,
    const float* __restrict__ maxpre, const int* __restrict__ zsrc,
    const float* __restrict__ Wh,  const float* __restrict__ bh,
    const float* __restrict__ Wst, const float* __restrict__ bst,
    const float* __restrict__ Wrc, const float* __restrict__ brc,
    const float* __restrict__ Wt,  const float* __restrict__ bt,
    float* __restrict__ zlog)
{
    __shared__ __align__(16) float whzlog_s[2*BB*DD];   // 128 KB loop-carried state
    __shared__ __align__(16) float h_s[2][DD];
    __shared__ __align__(16) float zu_s[DD], zv_s[DD];
    __shared__ __align__(16) float zupd_s[2][DD];
    __shared__ float tdi_s[8];
    __shared__ int   cnt_s[2*BB], ncorr_s[2*BB], zsrc_s[2*BB];

    const int t   = threadIdx.x;
    const int wv  = t >> 6;
    const int ln  = t & 63;
    const int rep = t & 7;
    const int d   = (t >> 3) & 127;

    // ---- persistent weights: 12 f32x4 (48 floats) + wt + biases ----
    f32x4 ws[4], wr[4], wh[4];
    #pragma unroll
    for (int m = 0; m < 4; ++m) {
        ws[m] = *(const f32x4*)(Wst + (size_t)d*DD + rep*16 + m*4);
        wr[m] = *(const f32x4*)(Wrc + (size_t)d*DD + rep*16 + m*4);
        wh[m] = *(const f32x4*)(Wh  + (size_t)d*DD + rep*16 + m*4);
    }
    const f32x4 wt = *(const f32x4*)(Wt + (size_t)d*4);
    const float bh_d = bh[d];
    const float bs_d = bst[d] + brc[d] + bt[d];

    if (t < 256)       { cnt_s[t] = nbr_cnt[t]; ncorr_s[t] = ncorr[t]; }
    else if (t < 512)  { zsrc_s[t-256] = zsrc[t-256]; }
    __syncthreads();

    // ---- software-pipelined loads: maxpre (waves 0/8), zu/zv (waves 1/9) ----
    float2 mnext = make_float2(0.f, 0.f);
    float2 znext = make_float2(0.f, 0.f);
    if (wv == 0 || wv == 8) {
        const int side = wv >> 3;
        mnext = *(const float2*)&maxpre[(size_t)side*DD + ln*2];
    } else if (wv == 1 || wv == 9) {
        const int r2 = wv >> 3;
        const int s = zsrc_s[r2];                 // step 0: always a z0 row
        const float* src = (s & SRCF) ? (zlog + (size_t)(s & 0xFFFF)*DD)
                                      : (z0   + (size_t)s*DD);
        znext = *(const float2*)&src[ln*2];
    }

    for (int i = 0; i < BB; ++i) {
        // ---- P0: h gather (maxpre + LDS corrections, batched); pipelined zu/zv; tdi ----
        if (wv == 0 || wv == 8) {
            const int side = wv >> 3;
            const int p = i*2 + side;
            float2 m = mnext;
            const int pn = ((i+1 < BB) ? (i+1) : i)*2 + side;
            mnext = *(const float2*)&maxpre[(size_t)pn*DD + ln*2];
            const int nc = ncorr_s[p];
            const int2* cpp = corr_pack + p*MAXDEG;
            int c = 0;
            for (; c + 3 < nc; c += 4) {           // batch: 4 indep L2 loads in flight
                const int2 c0 = cpp[c],   c1 = cpp[c+1];
                const int2 c2 = cpp[c+2], c3 = cpp[c+3];
                const float2 v0 = *(const float2*)&whzlog_s[c0.x*DD + ln*2];
                const float2 v1 = *(const float2*)&whzlog_s[c1.x*DD + ln*2];
                const float2 v2 = *(const float2*)&whzlog_s[c2.x*DD + ln*2];
                const float2 v3 = *(const float2*)&whzlog_s[c3.x*DD + ln*2];
                m.x = fmaxf(fmaxf(m.x, __int_as_float(c0.y)*v0.x),
                            fmaxf(__int_as_float(c1.y)*v1.x, __int_as_float(c2.y)*v2.x));
                m.x = fmaxf(m.x, __int_as_float(c3.y)*v3.x);
                m.y = fmaxf(fmaxf(m.y, __int_as_float(c0.y)*v0.y),
                            fmaxf(__int_as_float(c1.y)*v1.y, __int_as_float(c2.y)*v2.y));
                m.y = fmaxf(m.y, __int_as_float(c3.y)*v3.y);
            }
            for (; c < nc; ++c) {
                const int2 cp = cpp[c];
                const float qc = __int_as_float(cp.y);
                const float2 val = *(const float2*)&whzlog_s[cp.x*DD + ln*2];
                m.x = fmaxf(m.x, qc * val.x);
                m.y = fmaxf(m.y, qc * val.y);
            }
            if (cnt_s[p] > 0) {
                h_s[side][ln*2]   = 1.0f/(1.0f + expf(-m.x));
                h_s[side][ln*2+1] = 1.0f/(1.0f + expf(-m.y));
            } else {
                h_s[side][ln*2] = 0.0f; h_s[side][ln*2+1] = 0.0f;
            }
        } else if (wv == 1 || wv == 9) {
            const int r2 = wv >> 3;
            float* dst = r2 ? zv_s : zu_s;
            *(float2*)&dst[ln*2] = znext;          // prefetched at previous step's P2
        } else if (wv == 2 && ln < 8) {
            const float sd[4] = {50.f, 7.f, 15.f, 15.f};
            tdi_s[ln] = time_diff[i*8 + ln] / sd[ln & 3];
        }
        __syncthreads();   // B1

        // ---- P1: z_upd (both rows in-thread; weights register-resident) ----
        #pragma unroll
        for (int r2 = 0; r2 < 2; ++r2) {
            const float* hp = h_s[r2] + rep*16;
            const float* zp = (r2 ? zv_s : zu_s) + rep*16;
            float a = 0.f;
            #pragma unroll
            for (int m = 0; m < 4; ++m) {
                a += dot4v(*(const f32x4*)(hp + m*4), ws[m]);
                a += dot4v(*(const f32x4*)(zp + m*4), wr[m]);
            }
            a += __shfl_xor(a,1); a += __shfl_xor(a,2); a += __shfl_xor(a,4);
            if (rep == 0) {
                const float tdr = tdi_s[r2*4+0]*wt[0] + tdi_s[r2*4+1]*wt[1]
                                + tdi_s[r2*4+2]*wt[2] + tdi_s[r2*4+3]*wt[3];
                zupd_s[r2][d] = 1.0f/(1.0f + expf(-(a + bs_d + tdr)));
            }
        }
        __syncthreads();   // B2

        // ---- P2a: prefetch next step's zu/zv (zupd_s valid; older rows L2-hot) ----
        if (wv == 1 || wv == 9) {
            const int r2 = wv >> 3;
            const int inx = (i+1 < BB) ? (i+1) : i;
            const int s = zsrc_s[inx*2 + r2];
            if (s & SRCF) {
                const int row = s & 0xFFFF;
                if ((row >> 1) == i) znext = *(const float2*)&zupd_s[row & 1][ln*2];
                else                 znext = *(const float2*)&zlog[(size_t)row*DD + ln*2];
            } else {
                znext = *(const float2*)&z0[(size_t)s*DD + ln*2];
            }
        }
        // ---- P2b: Whz rows of the two updates -> whzlog_s (LDS) + zlog (global) ----
        #pragma unroll
        for (int r2 = 0; r2 < 2; ++r2) {
            const float* zp = zupd_s[r2] + rep*16;
            float a = 0.f;
            #pragma unroll
            for (int m = 0; m < 4; ++m)
                a += dot4v(*(const f32x4*)(zp + m*4), wh[m]);
            a += __shfl_xor(a,1); a += __shfl_xor(a,2); a += __shfl_xor(a,4);
            if (rep == 0) {
                const int row = i*2 + r2;
                whzlog_s[row*DD + d]        = a + bh_d;
                zlog[(size_t)row*DD + d]    = zupd_s[r2][d];
            }
        }
        __threadfence_block();   // zlog global stores visible to later-step gathers
        __syncthreads();   // B3 (also orders whzlog_s ds_writes)
    }
}

// ---------------- intensity epilogue (parallel, reads via src indices) ----------------
__global__ void lam_kernel(const float* __restrict__ z0, const float* __restrict__ zlog,
                           const int* __restrict__ zsrc, const int* __restrict__ negsrc,
                           const int* __restrict__ et,
                           const float* __restrict__ w0, const float* __restrict__ b0,
                           const float* __restrict__ w1, const float* __restrict__ b1,
                           const float* __restrict__ psi,
                           float* __restrict__ out)
{
    const int b   = blockIdx.x;
    const int i   = b / 11;
    const int col = b % 11;
    const int l   = threadIdx.x;

    auto rp = [&](int s) -> const float* {
        return (s & SRCF) ? (zlog + (size_t)(s & 0xFFFF)*DD) : (z0 + (size_t)s*DD);
    };
    const float* xu;
    const float* xv;
    if (col == 0) { xu = rp(zsrc[i*2]); xv = rp(zsrc[i*2+1]); }
    else {
        const int k = col - 1;
        xu = (k < QQ) ? rp(zsrc[i*2])            : rp(negsrc[i*2*QQ + k]);
        xv = (k < QQ) ? rp(negsrc[i*2*QQ + k])   : rp(zsrc[i*2+1]);
    }
    float g0 = xu[l]*w0[l] + xu[l+64]*w0[l+64] + xv[l]*w0[DD+l] + xv[l+64]*w0[DD+l+64];
    float g1 = xu[l]*w1[l] + xu[l+64]*w1[l+64] + xv[l]*w1[DD+l] + xv[l+64]*w1[DD+l+64];
    #pragma unroll
    for (int s = 32; s >= 1; s >>= 1) { g0 += __shfl_xor(g0, s); g1 += __shfl_xor(g1, s); }
    if (l == 0) {
        g0 += b0[0]; g1 += b1[0];
        const float p0 = psi[0], p1 = psi[1];
        float r;
        if (col == 0) {
            const int e = et[i];
            const float g = e ? g1 : g0;
            const float p = e ? p1 : p0;
            const float y = g / (p + 1e-7f);
            r = p * (fmaxf(y, 0.f) + log1pf(expf(-fabsf(y))));
        } else {
            const float y0 = g0 / (p0 + 1e-7f);
            const float y1 = g1 / (p1 + 1e-7f);
            r = p0 * (fmaxf(y0, 0.f) + log1pf(expf(-fabsf(y0))))
              + p1 * (fmaxf(y1, 0.f) + log1pf(expf(-fabsf(y1))));
        }
        out[i*11 + col] = r;
    }
}

extern "C" void kernel_launch(void* const* d_in, const int* in_sizes, int n_in,
                              void* d_out, int out_size, void* d_ws, size_t ws_size,
                              hipStream_t stream)
{
    const int*   u   = (const int*)d_in[0];
    const int*   v   = (const int*)d_in[1];
    const int*   et  = (const int*)d_in[2];
    const float* td  = (const float*)d_in[3];
    const int*   neg = (const int*)d_in[4];
    const float* z0  = (const float*)d_in[5];
    const float* A   = (const float*)d_in[6];
    const float* S   = (const float*)d_in[7];
    const float* w0  = (const float*)d_in[8];
    const float* b0  = (const float*)d_in[9];
    const float* w1  = (const float*)d_in[10];
    const float* b1  = (const float*)d_in[11];
    const float* psi = (const float*)d_in[12];
    const float* Wh  = (const float*)d_in[13];
    const float* bh  = (const float*)d_in[14];
    const float* Wst = (const float*)d_in[15];
    const float* bst = (const float*)d_in[16];
    const float* Wrc = (const float*)d_in[17];
    const float* brc = (const float*)d_in[18];
    const float* Wt  = (const float*)d_in[19];
    const float* bt  = (const float*)d_in[20];

    char* ws = (char*)d_ws;
    size_t off = 0;
    auto alloc = [&](size_t bytes) {
        void* p = ws + off;
        off = (off + bytes + 255) & ~(size_t)255;
        return p;
    };
    float* Whz0   = (float*)alloc((size_t)NN*DD*sizeof(float));
    float* maxpre = (float*)alloc((size_t)2*BB*DD*sizeof(float));
    float* zlog   = (float*)alloc((size_t)2*BB*DD*sizeof(float));
    int*   ncnt   = (int*)alloc((size_t)2*BB*sizeof(int));
    int*   ncorr  = (int*)alloc((size_t)2*BB*sizeof(int));
    int2*  cpk    = (int2*)alloc((size_t)2*BB*MAXDEG*sizeof(int2));
    int*   zsrc   = (int*)alloc((size_t)2*BB*sizeof(int));
    int*   negsrc = (int*)alloc((size_t)BB*2*QQ*sizeof(int));
    int2*  npk    = (int2*)alloc((size_t)2*BB*MAXDEG*sizeof(int2));

    whz_init<<<NN/16, 512, 0, stream>>>(z0, Wh, bh, Whz0);
    nbr_kernel<<<2*BB, 256, 0, stream>>>(u, v, A, S, ncnt, npk);
    src_kernel<<<BB, 64, 0, stream>>>(u, v, neg, zsrc, negsrc);
    prep_kernel<<<2*BB, 128, 0, stream>>>(u, v, ncnt, npk, Whz0, maxpre, ncorr, cpk);
    scan_kernel<<<1, 1024, 0, stream>>>(z0, td, ncnt, ncorr, cpk, maxpre, zsrc,
                                        Wh, bh, Wst, bst, Wrc, brc, Wt, bt, zlog);
    lam_kernel<<<BB*(1 + 2*QQ), 64, 0, stream>>>(z0, zlog, zsrc, negsrc, et,
                                                 w0, b0, w1, b1, psi, (float*)d_out);
}

// Round 11
// 304.535 us; speedup vs baseline: 1.5532x; 1.4796x over previous
//
#include <hip/hip_runtime.h>

#define NN 4096
#define DD 128
#define BB 128
#define QQ 5
#define MAXDEG 96
#define SRCF 0x40000000

typedef __attribute__((ext_vector_type(8))) short bf16x8;
typedef __attribute__((ext_vector_type(4))) float f32x4;

__device__ __forceinline__ float dot4f(float4 a, float4 b) {
    return a.x*b.x + a.y*b.y + a.z*b.z + a.w*b.w;
}
// round-to-nearest-even f32 -> bf16
__device__ __forceinline__ unsigned short bfr(float x) {
    unsigned u = __float_as_uint(x);
    return (unsigned short)((u + 0x7fffu + ((u >> 16) & 1u)) >> 16);
}
__device__ __forceinline__ unsigned int pack2bf(float lo, float hi) {
    return ((unsigned int)bfr(hi) << 16) | (unsigned int)bfr(lo);
}

// ---------------- neighbor-list precompute (parallel) ----------------
__global__ void nbr_kernel(const int* __restrict__ u, const int* __restrict__ v,
                           const float* __restrict__ A, const float* __restrict__ S,
                           int* __restrict__ nbr_cnt, int2* __restrict__ nbr_pack)
{
    __shared__ int   lcnt[257];
    __shared__ int   sidx[MAXDEG];
    __shared__ float sq[MAXDEG];
    __shared__ float ssum;
    __shared__ int   stot;

    const int p    = blockIdx.x;
    const int i    = p >> 1;
    const int side = p & 1;
    const int other = (side == 0) ? v[i] : u[i];   // side0 = agg(v), side1 = agg(u)
    const float* Arow = A + (size_t)other * NN;
    const float* Srow = S + (size_t)other * NN;
    const int tid = threadIdx.x;

    const int base = tid * 16;
    int c0 = 0;
    for (int j = 0; j < 16; ++j) c0 += (Arow[base + j] > 0.0f) ? 1 : 0;
    lcnt[tid] = c0;
    __syncthreads();
    if (tid == 0) {
        int s = 0;
        for (int k = 0; k < 256; ++k) { int c = lcnt[k]; lcnt[k] = s; s += c; }
        stot = s;
    }
    __syncthreads();
    int off = lcnt[tid];
    for (int j = 0; j < 16; ++j) {
        if (Arow[base + j] > 0.0f) {
            if (off < MAXDEG) sidx[off] = base + j;
            ++off;
        }
    }
    __syncthreads();
    int cnt = stot; if (cnt > MAXDEG) cnt = MAXDEG;
    for (int jj = tid; jj < cnt; jj += 256) sq[jj] = expf(Srow[sidx[jj]]);
    __syncthreads();
    if (tid == 0) {
        float s = 0.0f;
        for (int jj = 0; jj < cnt; ++jj) s += sq[jj];
        ssum = s + 1e-7f;
    }
    __syncthreads();
    for (int jj = tid; jj < cnt; jj += 256) {
        int2 pk;
        pk.x = sidx[jj];
        pk.y = __float_as_int(sq[jj] / ssum);
        nbr_pack[p * MAXDEG + jj] = pk;
    }
    if (tid == 0) nbr_cnt[p] = cnt;
}

// ---------------- Whz0[n][d] = z0[n].Wh[d] + bh[d] (parallel, f32 exact) ----------------
__global__ __launch_bounds__(512) void whz_init(
    const float* __restrict__ z0, const float* __restrict__ Wh, const float* __restrict__ bh,
    float* __restrict__ Whz0)
{
    const int t   = threadIdx.x;
    const int rep = t & 7;
    const int d0  = t >> 3;
    float4 wh0[4], wh1[4];
    #pragma unroll
    for (int m = 0; m < 4; ++m) {
        wh0[m] = *(const float4*)(Wh + (size_t)d0*DD + rep*16 + m*4);
        wh1[m] = *(const float4*)(Wh + (size_t)(d0+64)*DD + rep*16 + m*4);
    }
    const float bh0 = bh[d0], bh1 = bh[d0+64];
    const int r0 = blockIdx.x * 16;
    for (int r = r0; r < r0 + 16; ++r) {
        const float* zr = z0 + (size_t)r*DD + rep*16;
        float a0 = 0.f, a1 = 0.f;
        #pragma unroll
        for (int m = 0; m < 4; ++m) {
            float4 zz = *(const float4*)(zr + m*4);
            a0 += dot4f(zz, wh0[m]);
            a1 += dot4f(zz, wh1[m]);
        }
        a0 += __shfl_xor(a0,1); a0 += __shfl_xor(a0,2); a0 += __shfl_xor(a0,4);
        a1 += __shfl_xor(a1,1); a1 += __shfl_xor(a1,2); a1 += __shfl_xor(a1,4);
        if (rep == 0) {
            Whz0[(size_t)r*DD + d0]    = a0 + bh0;
            Whz0[(size_t)r*DD + d0+64] = a1 + bh1;
        }
    }
}

// ---------------- last-update sources for u,v,neg rows (parallel) ----------------
__global__ void src_kernel(const int* __restrict__ u, const int* __restrict__ v,
                           const int* __restrict__ neg,
                           int* __restrict__ zsrc, int* __restrict__ negsrc)
{
    const int i = blockIdx.x;
    const int k = threadIdx.x;
    if (k >= 2 + 2*QQ) return;
    const int n = (k == 0) ? u[i] : (k == 1) ? v[i] : neg[i*2*QQ + (k-2)];
    int s = n;
    for (int j = i-1; j >= 0; --j) {
        if (v[j] == n) { s = SRCF | (j*2 + 1); break; }
        if (u[j] == n) { s = SRCF | (j*2 + 0); break; }
    }
    if (k < 2) zsrc[i*2 + k] = s;
    else       negsrc[i*2*QQ + (k-2)] = s;
}

// ---------------- static-max + correction lists per (i,side) (parallel) ----------------
__global__ void prep_kernel(const int* __restrict__ u, const int* __restrict__ v,
                            const int* __restrict__ nbr_cnt, const int2* __restrict__ nbr_pack,
                            const float* __restrict__ Whz0,
                            float* __restrict__ maxpre, int* __restrict__ ncorr,
                            int2* __restrict__ corr_pack)
{
    __shared__ int   su[BB], sv[BB];
    __shared__ int   sidx[MAXDEG];
    __shared__ float sq[MAXDEG];
    __shared__ unsigned char cflag[MAXDEG];
    __shared__ int ccnt;

    const int p   = blockIdx.x;
    const int i   = p >> 1;
    const int tid = threadIdx.x;
    if (tid < BB) { su[tid] = u[tid]; sv[tid] = v[tid]; }
    if (tid == 0) ccnt = 0;
    const int cnt = nbr_cnt[p];
    for (int jj = tid; jj < cnt; jj += 128) {
        int2 pk = nbr_pack[p*MAXDEG + jj];
        sidx[jj] = pk.x; sq[jj] = __int_as_float(pk.y);
    }
    __syncthreads();
    for (int jj = tid; jj < cnt; jj += 128) {
        const int r = sidx[jj];
        int fs = -1;
        for (int j = i-1; j >= 0; --j) {
            if (sv[j] == r) { fs = j*2 + 1; break; }
            if (su[j] == r) { fs = j*2 + 0; break; }
        }
        if (fs >= 0) {
            const int pos = atomicAdd(&ccnt, 1);   // order-free (folded with commutative max)
            int2 cp; cp.x = fs; cp.y = __float_as_int(sq[jj]);
            corr_pack[p*MAXDEG + pos] = cp;
            cflag[jj] = 1;
        } else cflag[jj] = 0;
    }
    __syncthreads();
    const int d = tid;
    float m = -3.0e38f;
    for (int jj = 0; jj < cnt; ++jj)
        if (!cflag[jj]) m = fmaxf(m, sq[jj] * Whz0[(size_t)sidx[jj]*DD + d]);
    maxpre[(size_t)p*DD + d] = m;
    if (tid == 0) ncorr[p] = ccnt;
}

// ---------------- sequential scan: 1 block, 512 threads, MFMA weights-in-frags ----------------
// wave wv (0..7) owns output-dim m-tile [wv*16, wv*16+16).
// A-frags (persistent VGPR, bf16 pack-chains -> remat-proof):
//   afw[kt]: [Wst | Wrc] stacked K=256;  afh[kt]: Wh K=128.
// B operands (h, zu/zv, zupd) kept packed-bf16 in LDS -> B-frag = 1 ds_read_b128.
// P0 roles: wv0/1 = h gather sides, wv2/3 = zu/zv prefetch, wv4 = tdi -> tdw.
__global__ __launch_bounds__(512) void scan_kernel(
    const float* __restrict__ z0, const float* __restrict__ time_diff,
    const int* __restrict__ nbr_cnt, const int* __restrict__ ncorr,
    const int2* __restrict__ corr_pack,
    const float* __restrict__ maxpre, const int* __restrict__ zsrc,
    const float* __restrict__ Wh,  const float* __restrict__ bh,
    const float* __restrict__ Wst, const float* __restrict__ bst,
    const float* __restrict__ Wrc, const float* __restrict__ brc,
    const float* __restrict__ Wt,  const float* __restrict__ bt,
    float* __restrict__ zlog)
{
    __shared__ __align__(16) float whzlog_s[2*BB*DD];        // 128 KB loop-carried state (f32)
    __shared__ __align__(16) unsigned short h_sb[2][DD];     // bf16 h operands
    __shared__ __align__(16) unsigned short zub[DD];         // bf16 zu
    __shared__ __align__(16) unsigned short zvb[DD];         // bf16 zv
    __shared__ __align__(16) float zupd_s[2][DD];            // f32 (zlog + prefetch source)
    __shared__ __align__(16) unsigned short zupdb[2][DD];    // bf16 (P2 B-frags)
    __shared__ __align__(16) float tdw_s[2][DD];             // tdi @ Wt^T per step
    __shared__ int cnt_s[2*BB], ncorr_s[2*BB], zsrc_s[2*BB];

    const int t    = threadIdx.x;
    const int wv   = t >> 6;
    const int ln   = t & 63;
    const int arow = wv*16 + (ln & 15);     // A-frag row (m within tile = ln&15)
    const int kgrp = ln >> 4;               // k-group 0..3
    const int ncol = ln & 15;               // D col
    const int dbase = wv*16 + kgrp*4;       // D rows held by this lane (regs 0..3)

    // ---- persistent A-fragments (packed bf16 -> not rematerializable) ----
    bf16x8 afw[8];   // [Wst | Wrc], K=256
    #pragma unroll
    for (int kt = 0; kt < 8; ++kt) {
        const int kb = kt*32 + kgrp*8;
        const float* src = (kb < 128) ? (Wst + (size_t)arow*DD + kb)
                                      : (Wrc + (size_t)arow*DD + (kb - 128));
        #pragma unroll
        for (int j = 0; j < 8; ++j) afw[kt][j] = (short)bfr(src[j]);
    }
    bf16x8 afh[4];   // Wh, K=128
    #pragma unroll
    for (int kt = 0; kt < 4; ++kt) {
        const float* src = Wh + (size_t)arow*DD + kt*32 + kgrp*8;
        #pragma unroll
        for (int j = 0; j < 8; ++j) afh[kt][j] = (short)bfr(src[j]);
    }
    // per-lane epilogue constants for dims dbase..dbase+3
    f32x4 bsv, bhv;
    #pragma unroll
    for (int r = 0; r < 4; ++r) {
        bsv[r] = bst[dbase+r] + brc[dbase+r] + bt[dbase+r];
        bhv[r] = bh[dbase+r];
    }
    // wave-4 Wt slice (dims 2ln, 2ln+1)
    const float4 wtA = *(const float4*)(Wt + (size_t)(ln*2)*4);
    const float4 wtB = *(const float4*)(Wt + (size_t)(ln*2+1)*4);

    if (t < 256)      { cnt_s[t] = nbr_cnt[t]; ncorr_s[t] = ncorr[t]; }
    else              { zsrc_s[t-256] = zsrc[t-256]; }
    __syncthreads();

    // ---- software-pipelined loads: maxpre (wv0/1), zu/zv (wv2/3) ----
    float2 mnext = make_float2(0.f, 0.f);
    float2 znext = make_float2(0.f, 0.f);
    if (wv <= 1) {
        mnext = *(const float2*)&maxpre[(size_t)wv*DD + ln*2];
    } else if (wv <= 3) {
        const int s = zsrc_s[wv-2];                  // step 0 sources
        const float* src = (s & SRCF) ? (zlog + (size_t)(s & 0xFFFF)*DD)
                                      : (z0   + (size_t)s*DD);
        znext = *(const float2*)&src[ln*2];
    }

    for (int i = 0; i < BB; ++i) {
        // ================= P0 =================
        if (wv <= 1) {
            const int side = wv;
            const int p = i*2 + side;
            float2 m = mnext;
            const int pn = ((i+1 < BB) ? (i+1) : i)*2 + side;
            mnext = *(const float2*)&maxpre[(size_t)pn*DD + ln*2];
            const int nc = ncorr_s[p];
            const int2* cpp = corr_pack + p*MAXDEG;
            for (int c = 0; c < nc; ++c) {
                const int2 cp = cpp[c];
                const float qc = __int_as_float(cp.y);
                const float2 val = *(const float2*)&whzlog_s[cp.x*DD + ln*2];
                m.x = fmaxf(m.x, qc * val.x);
                m.y = fmaxf(m.y, qc * val.y);
            }
            float h0 = 0.f, h1 = 0.f;
            if (cnt_s[p] > 0) {
                h0 = 1.0f/(1.0f + expf(-m.x));
                h1 = 1.0f/(1.0f + expf(-m.y));
            }
            *(unsigned int*)&h_sb[side][ln*2] = pack2bf(h0, h1);
        } else if (wv <= 3) {
            unsigned short* dst = (wv == 3) ? zvb : zub;
            *(unsigned int*)&dst[ln*2] = pack2bf(znext.x, znext.y);
        } else if (wv == 4) {
            const float4 t0 = *(const float4*)&time_diff[i*8];
            const float4 t1 = *(const float4*)&time_diff[i*8 + 4];
            const float4 n0 = make_float4(t0.x/50.f, t0.y/7.f, t0.z/15.f, t0.w/15.f);
            const float4 n1 = make_float4(t1.x/50.f, t1.y/7.f, t1.z/15.f, t1.w/15.f);
            tdw_s[0][ln*2]   = dot4f(n0, wtA);
            tdw_s[0][ln*2+1] = dot4f(n0, wtB);
            tdw_s[1][ln*2]   = dot4f(n1, wtA);
            tdw_s[1][ln*2+1] = dot4f(n1, wtB);
        }
        __syncthreads();   // B1

        // ================= P1: z_upd GEMM (K=256) =================
        {
            const int cc = (ncol < 2) ? ncol : 0;
            const unsigned short* hp = &h_sb[cc][0];
            const unsigned short* zp = cc ? zvb : zub;
            f32x4 acc = {0.f, 0.f, 0.f, 0.f};
            #pragma unroll
            for (int kt = 0; kt < 4; ++kt) {
                bf16x8 b = *(const bf16x8*)&hp[kt*32 + kgrp*8];
                acc = __builtin_amdgcn_mfma_f32_16x16x32_bf16(afw[kt], b, acc, 0, 0, 0);
            }
            #pragma unroll
            for (int kt = 4; kt < 8; ++kt) {
                bf16x8 b = *(const bf16x8*)&zp[(kt-4)*32 + kgrp*8];
                acc = __builtin_amdgcn_mfma_f32_16x16x32_bf16(afw[kt], b, acc, 0, 0, 0);
            }
            if (ncol < 2) {
                const f32x4 tdwv = *(const f32x4*)&tdw_s[ncol][dbase];
                f32x4 zu4;
                #pragma unroll
                for (int r = 0; r < 4; ++r)
                    zu4[r] = 1.0f/(1.0f + expf(-(acc[r] + bsv[r] + tdwv[r])));
                *(f32x4*)&zupd_s[ncol][dbase] = zu4;
                uint2 pk;
                pk.x = pack2bf(zu4[0], zu4[1]);
                pk.y = pack2bf(zu4[2], zu4[3]);
                *(uint2*)&zupdb[ncol][dbase] = pk;
            }
        }
        __syncthreads();   // B2

        // ---- P2a: prefetch next step's zu/zv (wv2/3) ----
        if (wv == 2 || wv == 3) {
            const int r2 = wv - 2;
            const int inx = (i+1 < BB) ? (i+1) : i;
            const int s = zsrc_s[inx*2 + r2];
            if (s & SRCF) {
                const int row = s & 0xFFFF;
                if ((row >> 1) == i) znext = *(const float2*)&zupd_s[row & 1][ln*2];
                else                 znext = *(const float2*)&zlog[(size_t)row*DD + ln*2];
            } else {
                znext = *(const float2*)&z0[(size_t)s*DD + ln*2];
            }
        }
        // ---- P2b: Whz GEMM (K=128) -> whzlog_s + zlog ----
        {
            const int cc = (ncol < 2) ? ncol : 0;
            const unsigned short* up = &zupdb[cc][0];
            f32x4 acc2 = {0.f, 0.f, 0.f, 0.f};
            #pragma unroll
            for (int kt = 0; kt < 4; ++kt) {
                bf16x8 b = *(const bf16x8*)&up[kt*32 + kgrp*8];
                acc2 = __builtin_amdgcn_mfma_f32_16x16x32_bf16(afh[kt], b, acc2, 0, 0, 0);
            }
            if (ncol < 2) {
                const int row = i*2 + ncol;
                f32x4 wz;
                #pragma unroll
                for (int r = 0; r < 4; ++r) wz[r] = acc2[r] + bhv[r];
                *(f32x4*)&whzlog_s[row*DD + dbase] = wz;
                const f32x4 zu4 = *(const f32x4*)&zupd_s[ncol][dbase];
                *(f32x4*)&zlog[(size_t)row*DD + dbase] = zu4;
            }
        }
        __threadfence_block();   // zlog global stores visible to later-step reads
        __syncthreads();   // B3
    }
}

// ---------------- intensity epilogue (parallel, reads via src indices) ----------------
__global__ void lam_kernel(const float* __restrict__ z0, const float* __restrict__ zlog,
                           const int* __restrict__ zsrc, const int* __restrict__ negsrc,
                           const int* __restrict__ et,
                           const float* __restrict__ w0, const float* __restrict__ b0,
                           const float* __restrict__ w1, const float* __restrict__ b1,
                           const float* __restrict__ psi,
                           float* __restrict__ out)
{
    const int b   = blockIdx.x;
    const int i   = b / 11;
    const int col = b % 11;
    const int l   = threadIdx.x;

    auto rp = [&](int s) -> const float* {
        return (s & SRCF) ? (zlog + (size_t)(s & 0xFFFF)*DD) : (z0 + (size_t)s*DD);
    };
    const float* xu;
    const float* xv;
    if (col == 0) { xu = rp(zsrc[i*2]); xv = rp(zsrc[i*2+1]); }
    else {
        const int k = col - 1;
        xu = (k < QQ) ? rp(zsrc[i*2])            : rp(negsrc[i*2*QQ + k]);
        xv = (k < QQ) ? rp(negsrc[i*2*QQ + k])   : rp(zsrc[i*2+1]);
    }
    float g0 = xu[l]*w0[l] + xu[l+64]*w0[l+64] + xv[l]*w0[DD+l] + xv[l+64]*w0[DD+l+64];
    float g1 = xu[l]*w1[l] + xu[l+64]*w1[l+64] + xv[l]*w1[DD+l] + xv[l+64]*w1[DD+l+64];
    #pragma unroll
    for (int s = 32; s >= 1; s >>= 1) { g0 += __shfl_xor(g0, s); g1 += __shfl_xor(g1, s); }
    if (l == 0) {
        g0 += b0[0]; g1 += b1[0];
        const float p0 = psi[0], p1 = psi[1];
        float r;
        if (col == 0) {
            const int e = et[i];
            const float g = e ? g1 : g0;
            const float p = e ? p1 : p0;
            const float y = g / (p + 1e-7f);
            r = p * (fmaxf(y, 0.f) + log1pf(expf(-fabsf(y))));
        } else {
            const float y0 = g0 / (p0 + 1e-7f);
            const float y1 = g1 / (p1 + 1e-7f);
            r = p0 * (fmaxf(y0, 0.f) + log1pf(expf(-fabsf(y0))))
              + p1 * (fmaxf(y1, 0.f) + log1pf(expf(-fabsf(y1))));
        }
        out[i*11 + col] = r;
    }
}

extern "C" void kernel_launch(void* const* d_in, const int* in_sizes, int n_in,
                              void* d_out, int out_size, void* d_ws, size_t ws_size,
                              hipStream_t stream)
{
    const int*   u   = (const int*)d_in[0];
    const int*   v   = (const int*)d_in[1];
    const int*   et  = (const int*)d_in[2];
    const float* td  = (const float*)d_in[3];
    const int*   neg = (const int*)d_in[4];
    const float* z0  = (const float*)d_in[5];
    const float* A   = (const float*)d_in[6];
    const float* S   = (const float*)d_in[7];
    const float* w0  = (const float*)d_in[8];
    const float* b0  = (const float*)d_in[9];
    const float* w1  = (const float*)d_in[10];
    const float* b1  = (const float*)d_in[11];
    const float* psi = (const float*)d_in[12];
    const float* Wh  = (const float*)d_in[13];
    const float* bh  = (const float*)d_in[14];
    const float* Wst = (const float*)d_in[15];
    const float* bst = (const float*)d_in[16];
    const float* Wrc = (const float*)d_in[17];
    const float* brc = (const float*)d_in[18];
    const float* Wt  = (const float*)d_in[19];
    const float* bt  = (const float*)d_in[20];

    char* ws = (char*)d_ws;
    size_t off = 0;
    auto alloc = [&](size_t bytes) {
        void* p = ws + off;
        off = (off + bytes + 255) & ~(size_t)255;
        return p;
    };
    float* Whz0   = (float*)alloc((size_t)NN*DD*sizeof(float));
    float* maxpre = (float*)alloc((size_t)2*BB*DD*sizeof(float));
    float* zlog   = (float*)alloc((size_t)2*BB*DD*sizeof(float));
    int*   ncnt   = (int*)alloc((size_t)2*BB*sizeof(int));
    int*   ncorr  = (int*)alloc((size_t)2*BB*sizeof(int));
    int2*  cpk    = (int2*)alloc((size_t)2*BB*MAXDEG*sizeof(int2));
    int*   zsrc   = (int*)alloc((size_t)2*BB*sizeof(int));
    int*   negsrc = (int*)alloc((size_t)BB*2*QQ*sizeof(int));
    int2*  npk    = (int2*)alloc((size_t)2*BB*MAXDEG*sizeof(int2));

    whz_init<<<NN/16, 512, 0, stream>>>(z0, Wh, bh, Whz0);
    nbr_kernel<<<2*BB, 256, 0, stream>>>(u, v, A, S, ncnt, npk);
    src_kernel<<<BB, 64, 0, stream>>>(u, v, neg, zsrc, negsrc);
    prep_kernel<<<2*BB, 128, 0, stream>>>(u, v, ncnt, npk, Whz0, maxpre, ncorr, cpk);
    scan_kernel<<<1, 512, 0, stream>>>(z0, td, ncnt, ncorr, cpk, maxpre, zsrc,
                                       Wh, bh, Wst, bst, Wrc, brc, Wt, bt, zlog);
    lam_kernel<<<BB*(1 + 2*QQ), 64, 0, stream>>>(z0, zlog, zsrc, negsrc, et,
                                                 w0, b0, w1, b1, psi, (float*)d_out);
}

// Round 12
// 272.961 us; speedup vs baseline: 1.7329x; 1.1157x over previous
//
#include <hip/hip_runtime.h>

#define NN 4096
#define DD 128
#define BB 128
#define QQ 5
#define MAXDEG 96
#define SRCF 0x40000000

typedef __attribute__((ext_vector_type(8))) short bf16x8;
typedef __attribute__((ext_vector_type(4))) float f32x4;

__device__ __forceinline__ float dot4f(float4 a, float4 b) {
    return a.x*b.x + a.y*b.y + a.z*b.z + a.w*b.w;
}
// round-to-nearest-even f32 -> bf16
__device__ __forceinline__ unsigned short bfr(float x) {
    unsigned u = __float_as_uint(x);
    return (unsigned short)((u + 0x7fffu + ((u >> 16) & 1u)) >> 16);
}
__device__ __forceinline__ unsigned int pack2bf(float lo, float hi) {
    return ((unsigned int)bfr(hi) << 16) | (unsigned int)bfr(lo);
}

// ---------------- neighbor-list precompute (parallel) ----------------
__global__ void nbr_kernel(const int* __restrict__ u, const int* __restrict__ v,
                           const float* __restrict__ A, const float* __restrict__ S,
                           int* __restrict__ nbr_cnt, int2* __restrict__ nbr_pack)
{
    __shared__ int   lcnt[257];
    __shared__ int   sidx[MAXDEG];
    __shared__ float sq[MAXDEG];
    __shared__ float ssum;
    __shared__ int   stot;

    const int p    = blockIdx.x;
    const int i    = p >> 1;
    const int side = p & 1;
    const int other = (side == 0) ? v[i] : u[i];   // side0 = agg(v), side1 = agg(u)
    const float* Arow = A + (size_t)other * NN;
    const float* Srow = S + (size_t)other * NN;
    const int tid = threadIdx.x;

    const int base = tid * 16;
    int c0 = 0;
    for (int j = 0; j < 16; ++j) c0 += (Arow[base + j] > 0.0f) ? 1 : 0;
    lcnt[tid] = c0;
    __syncthreads();
    if (tid == 0) {
        int s = 0;
        for (int k = 0; k < 256; ++k) { int c = lcnt[k]; lcnt[k] = s; s += c; }
        stot = s;
    }
    __syncthreads();
    int off = lcnt[tid];
    for (int j = 0; j < 16; ++j) {
        if (Arow[base + j] > 0.0f) {
            if (off < MAXDEG) sidx[off] = base + j;
            ++off;
        }
    }
    __syncthreads();
    int cnt = stot; if (cnt > MAXDEG) cnt = MAXDEG;
    for (int jj = tid; jj < cnt; jj += 256) sq[jj] = expf(Srow[sidx[jj]]);
    __syncthreads();
    if (tid == 0) {
        float s = 0.0f;
        for (int jj = 0; jj < cnt; ++jj) s += sq[jj];
        ssum = s + 1e-7f;
    }
    __syncthreads();
    for (int jj = tid; jj < cnt; jj += 256) {
        int2 pk;
        pk.x = sidx[jj];
        pk.y = __float_as_int(sq[jj] / ssum);
        nbr_pack[p * MAXDEG + jj] = pk;
    }
    if (tid == 0) nbr_cnt[p] = cnt;
}

// ---------------- Whz0[n][d] = z0[n].Wh[d] + bh[d] (parallel, f32 exact) ----------------
__global__ __launch_bounds__(512) void whz_init(
    const float* __restrict__ z0, const float* __restrict__ Wh, const float* __restrict__ bh,
    float* __restrict__ Whz0)
{
    const int t   = threadIdx.x;
    const int rep = t & 7;
    const int d0  = t >> 3;
    float4 wh0[4], wh1[4];
    #pragma unroll
    for (int m = 0; m < 4; ++m) {
        wh0[m] = *(const float4*)(Wh + (size_t)d0*DD + rep*16 + m*4);
        wh1[m] = *(const float4*)(Wh + (size_t)(d0+64)*DD + rep*16 + m*4);
    }
    const float bh0 = bh[d0], bh1 = bh[d0+64];
    const int r0 = blockIdx.x * 16;
    for (int r = r0; r < r0 + 16; ++r) {
        const float* zr = z0 + (size_t)r*DD + rep*16;
        float a0 = 0.f, a1 = 0.f;
        #pragma unroll
        for (int m = 0; m < 4; ++m) {
            float4 zz = *(const float4*)(zr + m*4);
            a0 += dot4f(zz, wh0[m]);
            a1 += dot4f(zz, wh1[m]);
        }
        a0 += __shfl_xor(a0,1); a0 += __shfl_xor(a0,2); a0 += __shfl_xor(a0,4);
        a1 += __shfl_xor(a1,1); a1 += __shfl_xor(a1,2); a1 += __shfl_xor(a1,4);
        if (rep == 0) {
            Whz0[(size_t)r*DD + d0]    = a0 + bh0;
            Whz0[(size_t)r*DD + d0+64] = a1 + bh1;
        }
    }
}

// ---------------- last-update sources for u,v,neg rows (parallel) ----------------
__global__ void src_kernel(const int* __restrict__ u, const int* __restrict__ v,
                           const int* __restrict__ neg,
                           int* __restrict__ zsrc, int* __restrict__ negsrc)
{
    const int i = blockIdx.x;
    const int k = threadIdx.x;
    if (k >= 2 + 2*QQ) return;
    const int n = (k == 0) ? u[i] : (k == 1) ? v[i] : neg[i*2*QQ + (k-2)];
    int s = n;
    for (int j = i-1; j >= 0; --j) {
        if (v[j] == n) { s = SRCF | (j*2 + 1); break; }
        if (u[j] == n) { s = SRCF | (j*2 + 0); break; }
    }
    if (k < 2) zsrc[i*2 + k] = s;
    else       negsrc[i*2*QQ + (k-2)] = s;
}

// ---------------- static-max + correction lists per (i,side) (parallel) ----------------
__global__ void prep_kernel(const int* __restrict__ u, const int* __restrict__ v,
                            const int* __restrict__ nbr_cnt, const int2* __restrict__ nbr_pack,
                            const float* __restrict__ Whz0,
                            float* __restrict__ maxpre, int* __restrict__ ncorr,
                            int2* __restrict__ corr_pack)
{
    __shared__ int   su[BB], sv[BB];
    __shared__ int   sidx[MAXDEG];
    __shared__ float sq[MAXDEG];
    __shared__ unsigned char cflag[MAXDEG];
    __shared__ int ccnt;

    const int p   = blockIdx.x;
    const int i   = p >> 1;
    const int tid = threadIdx.x;
    if (tid < BB) { su[tid] = u[tid]; sv[tid] = v[tid]; }
    if (tid == 0) ccnt = 0;
    const int cnt = nbr_cnt[p];
    for (int jj = tid; jj < cnt; jj += 128) {
        int2 pk = nbr_pack[p*MAXDEG + jj];
        sidx[jj] = pk.x; sq[jj] = __int_as_float(pk.y);
    }
    __syncthreads();
    for (int jj = tid; jj < cnt; jj += 128) {
        const int r = sidx[jj];
        int fs = -1;
        for (int j = i-1; j >= 0; --j) {
            if (sv[j] == r) { fs = j*2 + 1; break; }
            if (su[j] == r) { fs = j*2 + 0; break; }
        }
        if (fs >= 0) {
            const int pos = atomicAdd(&ccnt, 1);   // order-free (folded with commutative max)
            int2 cp; cp.x = fs; cp.y = __float_as_int(sq[jj]);
            corr_pack[p*MAXDEG + pos] = cp;
            cflag[jj] = 1;
        } else cflag[jj] = 0;
    }
    __syncthreads();
    const int d = tid;
    float m = -3.0e38f;
    for (int jj = 0; jj < cnt; ++jj)
        if (!cflag[jj]) m = fmaxf(m, sq[jj] * Whz0[(size_t)sidx[jj]*DD + d]);
    maxpre[(size_t)p*DD + d] = m;
    if (tid == 0) ncorr[p] = ccnt;
}

// ---------------- sequential scan: 1 block, 512 threads, fully on-CU state ----------------
// wave wv (0..7) owns output-dim m-tile [wv*16, wv*16+16).
// A-frags persistent in VGPRs (bf16 pack-chains, remat-proof — r11 proven, VGPR=88).
// Loop-carried state (whz, zlog) lives in LDS as bf16; zlog global store is
// fire-and-forget (lam reads it post-kernel) -> no threadfence, no vmcnt drain.
// P0 roles: wv0/1 = h gather sides, wv2/3 = zu/zv prefetch, wv4 = tdi -> tdw.
__global__ __launch_bounds__(512) void scan_kernel(
    const float* __restrict__ z0, const float* __restrict__ time_diff,
    const int* __restrict__ nbr_cnt, const int* __restrict__ ncorr,
    const int2* __restrict__ corr_pack,
    const float* __restrict__ maxpre, const int* __restrict__ zsrc,
    const float* __restrict__ Wh,  const float* __restrict__ bh,
    const float* __restrict__ Wst, const float* __restrict__ bst,
    const float* __restrict__ Wrc, const float* __restrict__ brc,
    const float* __restrict__ Wt,  const float* __restrict__ bt,
    float* __restrict__ zlog)
{
    __shared__ __align__(16) unsigned short whz_sb[2*BB*DD];   // 64 KB whz log (bf16)
    __shared__ __align__(16) unsigned short zlog_sb[2*BB*DD];  // 64 KB z log (bf16)
    __shared__ __align__(16) unsigned short h_sb[2][DD];       // bf16 h operands
    __shared__ __align__(16) unsigned short zub[DD];           // bf16 zu
    __shared__ __align__(16) unsigned short zvb[DD];           // bf16 zv
    __shared__ __align__(16) float zupd_s[2][DD];              // f32 (store + same-step prefetch)
    __shared__ __align__(16) unsigned short zupdb[2][DD];      // bf16 (P2 B-frags)
    __shared__ __align__(16) float tdw_s[2][DD];               // tdi @ Wt^T per step
    __shared__ int cnt_s[2*BB], ncorr_s[2*BB], zsrc_s[2*BB];

    const int t    = threadIdx.x;
    const int wv   = t >> 6;
    const int ln   = t & 63;
    const int arow = wv*16 + (ln & 15);     // A-frag row
    const int kgrp = ln >> 4;               // k-group 0..3
    const int ncol = ln & 15;               // D col
    const int dbase = wv*16 + kgrp*4;       // D rows held by this lane

    // ---- persistent A-fragments (packed bf16 -> not rematerializable) ----
    bf16x8 afw[8];   // [Wst | Wrc], K=256
    #pragma unroll
    for (int kt = 0; kt < 8; ++kt) {
        const int kb = kt*32 + kgrp*8;
        const float* src = (kb < 128) ? (Wst + (size_t)arow*DD + kb)
                                      : (Wrc + (size_t)arow*DD + (kb - 128));
        #pragma unroll
        for (int j = 0; j < 8; ++j) afw[kt][j] = (short)bfr(src[j]);
    }
    bf16x8 afh[4];   // Wh, K=128
    #pragma unroll
    for (int kt = 0; kt < 4; ++kt) {
        const float* src = Wh + (size_t)arow*DD + kt*32 + kgrp*8;
        #pragma unroll
        for (int j = 0; j < 8; ++j) afh[kt][j] = (short)bfr(src[j]);
    }
    f32x4 bsv, bhv;
    #pragma unroll
    for (int r = 0; r < 4; ++r) {
        bsv[r] = bst[dbase+r] + brc[dbase+r] + bt[dbase+r];
        bhv[r] = bh[dbase+r];
    }
    const float4 wtA = *(const float4*)(Wt + (size_t)(ln*2)*4);
    const float4 wtB = *(const float4*)(Wt + (size_t)(ln*2+1)*4);

    if (t < 256)      { cnt_s[t] = nbr_cnt[t]; ncorr_s[t] = ncorr[t]; }
    else              { zsrc_s[t-256] = zsrc[t-256]; }
    __syncthreads();

    // ---- software-pipelined loads: maxpre+corr (wv0/1), zu/zv (wv2/3) ----
    float2 mnext = make_float2(0.f, 0.f);
    float2 znext = make_float2(0.f, 0.f);
    int2 cpf0, cpf1, cpf2, cpf3;            // prefetched correction entries (step i)
    if (wv <= 1) {
        mnext = *(const float2*)&maxpre[(size_t)wv*DD + ln*2];
        const int2* cpp = corr_pack + (size_t)wv*MAXDEG;
        cpf0 = cpp[0]; cpf1 = cpp[1]; cpf2 = cpp[2]; cpf3 = cpp[3];
    } else if (wv <= 3) {
        const int s = zsrc_s[wv-2];
        const float* src = (s & SRCF) ? (zlog + (size_t)(s & 0xFFFF)*DD)
                                      : (z0   + (size_t)s*DD);
        znext = *(const float2*)&src[ln*2];
    }

    for (int i = 0; i < BB; ++i) {
        // ================= P0 =================
        if (wv <= 1) {
            const int side = wv;
            const int p = i*2 + side;
            float2 m = mnext;
            const int pn = ((i+1 < BB) ? (i+1) : i)*2 + side;
            mnext = *(const float2*)&maxpre[(size_t)pn*DD + ln*2];
            const int nc = ncorr_s[p];
            // prefetched corr entries (cover nc<=4; tail from global, rare)
            const int2 cf[4] = {cpf0, cpf1, cpf2, cpf3};
            #pragma unroll
            for (int j = 0; j < 4; ++j) {
                if (j < nc) {
                    const float qc = __int_as_float(cf[j].y);
                    const unsigned pk = *(const unsigned*)&whz_sb[cf[j].x*DD + ln*2];
                    m.x = fmaxf(m.x, qc * __uint_as_float(pk << 16));
                    m.y = fmaxf(m.y, qc * __uint_as_float(pk & 0xffff0000u));
                }
            }
            const int2* cpp = corr_pack + (size_t)p*MAXDEG;
            for (int c = 4; c < nc; ++c) {
                const int2 cp = cpp[c];
                const float qc = __int_as_float(cp.y);
                const unsigned pk = *(const unsigned*)&whz_sb[cp.x*DD + ln*2];
                m.x = fmaxf(m.x, qc * __uint_as_float(pk << 16));
                m.y = fmaxf(m.y, qc * __uint_as_float(pk & 0xffff0000u));
            }
            float h0 = 0.f, h1 = 0.f;
            if (cnt_s[p] > 0) {
                h0 = 1.0f/(1.0f + __expf(-m.x));
                h1 = 1.0f/(1.0f + __expf(-m.y));
            }
            *(unsigned int*)&h_sb[side][ln*2] = pack2bf(h0, h1);
        } else if (wv <= 3) {
            unsigned short* dst = (wv == 3) ? zvb : zub;
            *(unsigned int*)&dst[ln*2] = pack2bf(znext.x, znext.y);
        } else if (wv == 4) {
            const float4 t0 = *(const float4*)&time_diff[i*8];
            const float4 t1 = *(const float4*)&time_diff[i*8 + 4];
            const float4 n0 = make_float4(t0.x/50.f, t0.y/7.f, t0.z/15.f, t0.w/15.f);
            const float4 n1 = make_float4(t1.x/50.f, t1.y/7.f, t1.z/15.f, t1.w/15.f);
            tdw_s[0][ln*2]   = dot4f(n0, wtA);
            tdw_s[0][ln*2+1] = dot4f(n0, wtB);
            tdw_s[1][ln*2]   = dot4f(n1, wtA);
            tdw_s[1][ln*2+1] = dot4f(n1, wtB);
        }
        __syncthreads();   // B1

        // ================= P1: z_upd GEMM (K=256) =================
        {
            const int cc = (ncol < 2) ? ncol : 0;
            const unsigned short* hp = &h_sb[cc][0];
            const unsigned short* zp = cc ? zvb : zub;
            f32x4 acc = {0.f, 0.f, 0.f, 0.f};
            #pragma unroll
            for (int kt = 0; kt < 4; ++kt) {
                bf16x8 b = *(const bf16x8*)&hp[kt*32 + kgrp*8];
                acc = __builtin_amdgcn_mfma_f32_16x16x32_bf16(afw[kt], b, acc, 0, 0, 0);
            }
            #pragma unroll
            for (int kt = 4; kt < 8; ++kt) {
                bf16x8 b = *(const bf16x8*)&zp[(kt-4)*32 + kgrp*8];
                acc = __builtin_amdgcn_mfma_f32_16x16x32_bf16(afw[kt], b, acc, 0, 0, 0);
            }
            if (ncol < 2) {
                const f32x4 tdwv = *(const f32x4*)&tdw_s[ncol][dbase];
                f32x4 zu4;
                #pragma unroll
                for (int r = 0; r < 4; ++r)
                    zu4[r] = 1.0f/(1.0f + __expf(-(acc[r] + bsv[r] + tdwv[r])));
                *(f32x4*)&zupd_s[ncol][dbase] = zu4;
                uint2 pk;
                pk.x = pack2bf(zu4[0], zu4[1]);
                pk.y = pack2bf(zu4[2], zu4[3]);
                *(uint2*)&zupdb[ncol][dbase] = pk;
            }
        }
        __syncthreads();   // B2

        // ---- P2a: prefetch next step's inputs (waves 0-3; overlapped with P2b) ----
        if (wv <= 1) {
            const int pn2 = ((i+1 < BB) ? (i+1) : i)*2 + wv;
            const int2* cppn = corr_pack + (size_t)pn2*MAXDEG;
            cpf0 = cppn[0]; cpf1 = cppn[1]; cpf2 = cppn[2]; cpf3 = cppn[3];
        } else if (wv == 2 || wv == 3) {
            const int r2 = wv - 2;
            const int inx = (i+1 < BB) ? (i+1) : i;
            const int s = zsrc_s[inx*2 + r2];
            if (s & SRCF) {
                const int row = s & 0xFFFF;
                if ((row >> 1) == i) {
                    znext = *(const float2*)&zupd_s[row & 1][ln*2];
                } else {
                    const unsigned pk = *(const unsigned*)&zlog_sb[row*DD + ln*2];
                    znext.x = __uint_as_float(pk << 16);
                    znext.y = __uint_as_float(pk & 0xffff0000u);
                }
            } else {
                znext = *(const float2*)&z0[(size_t)s*DD + ln*2];
            }
        }
        // ---- P2b: Whz GEMM (K=128) -> whz_sb + zlog_sb (LDS) + zlog (global, no fence) ----
        {
            const int cc = (ncol < 2) ? ncol : 0;
            const unsigned short* up = &zupdb[cc][0];
            f32x4 acc2 = {0.f, 0.f, 0.f, 0.f};
            #pragma unroll
            for (int kt = 0; kt < 4; ++kt) {
                bf16x8 b = *(const bf16x8*)&up[kt*32 + kgrp*8];
                acc2 = __builtin_amdgcn_mfma_f32_16x16x32_bf16(afh[kt], b, acc2, 0, 0, 0);
            }
            if (ncol < 2) {
                const int row = i*2 + ncol;
                uint2 wpk;
                wpk.x = pack2bf(acc2[0] + bhv[0], acc2[1] + bhv[1]);
                wpk.y = pack2bf(acc2[2] + bhv[2], acc2[3] + bhv[3]);
                *(uint2*)&whz_sb[row*DD + dbase] = wpk;
                const f32x4 zu4 = *(const f32x4*)&zupd_s[ncol][dbase];
                uint2 zpk;
                zpk.x = pack2bf(zu4[0], zu4[1]);
                zpk.y = pack2bf(zu4[2], zu4[3]);
                *(uint2*)&zlog_sb[row*DD + dbase] = zpk;
                *(f32x4*)&zlog[(size_t)row*DD + dbase] = zu4;   // fire-and-forget
            }
        }
        __syncthreads();   // B3 (orders all LDS writes for next step's reads)
    }
}

// ---------------- intensity epilogue (parallel, reads via src indices) ----------------
__global__ void lam_kernel(const float* __restrict__ z0, const float* __restrict__ zlog,
                           const int* __restrict__ zsrc, const int* __restrict__ negsrc,
                           const int* __restrict__ et,
                           const float* __restrict__ w0, const float* __restrict__ b0,
                           const float* __restrict__ w1, const float* __restrict__ b1,
                           const float* __restrict__ psi,
                           float* __restrict__ out)
{
    const int b   = blockIdx.x;
    const int i   = b / 11;
    const int col = b % 11;
    const int l   = threadIdx.x;

    auto rp = [&](int s) -> const float* {
        return (s & SRCF) ? (zlog + (size_t)(s & 0xFFFF)*DD) : (z0 + (size_t)s*DD);
    };
    const float* xu;
    const float* xv;
    if (col == 0) { xu = rp(zsrc[i*2]); xv = rp(zsrc[i*2+1]); }
    else {
        const int k = col - 1;
        xu = (k < QQ) ? rp(zsrc[i*2])            : rp(negsrc[i*2*QQ + k]);
        xv = (k < QQ) ? rp(negsrc[i*2*QQ + k])   : rp(zsrc[i*2+1]);
    }
    float g0 = xu[l]*w0[l] + xu[l+64]*w0[l+64] + xv[l]*w0[DD+l] + xv[l+64]*w0[DD+l+64];
    float g1 = xu[l]*w1[l] + xu[l+64]*w1[l+64] + xv[l]*w1[DD+l] + xv[l+64]*w1[DD+l+64];
    #pragma unroll
    for (int s = 32; s >= 1; s >>= 1) { g0 += __shfl_xor(g0, s); g1 += __shfl_xor(g1, s); }
    if (l == 0) {
        g0 += b0[0]; g1 += b1[0];
        const float p0 = psi[0], p1 = psi[1];
        float r;
        if (col == 0) {
            const int e = et[i];
            const float g = e ? g1 : g0;
            const float p = e ? p1 : p0;
            const float y = g / (p + 1e-7f);
            r = p * (fmaxf(y, 0.f) + log1pf(expf(-fabsf(y))));
        } else {
            const float y0 = g0 / (p0 + 1e-7f);
            const float y1 = g1 / (p1 + 1e-7f);
            r = p0 * (fmaxf(y0, 0.f) + log1pf(expf(-fabsf(y0))))
              + p1 * (fmaxf(y1, 0.f) + log1pf(expf(-fabsf(y1))));
        }
        out[i*11 + col] = r;
    }
}

extern "C" void kernel_launch(void* const* d_in, const int* in_sizes, int n_in,
                              void* d_out, int out_size, void* d_ws, size_t ws_size,
                              hipStream_t stream)
{
    const int*   u   = (const int*)d_in[0];
    const int*   v   = (const int*)d_in[1];
    const int*   et  = (const int*)d_in[2];
    const float* td  = (const float*)d_in[3];
    const int*   neg = (const int*)d_in[4];
    const float* z0  = (const float*)d_in[5];
    const float* A   = (const float*)d_in[6];
    const float* S   = (const float*)d_in[7];
    const float* w0  = (const float*)d_in[8];
    const float* b0  = (const float*)d_in[9];
    const float* w1  = (const float*)d_in[10];
    const float* b1  = (const float*)d_in[11];
    const float* psi = (const float*)d_in[12];
    const float* Wh  = (const float*)d_in[13];
    const float* bh  = (const float*)d_in[14];
    const float* Wst = (const float*)d_in[15];
    const float* bst = (const float*)d_in[16];
    const float* Wrc = (const float*)d_in[17];
    const float* brc = (const float*)d_in[18];
    const float* Wt  = (const float*)d_in[19];
    const float* bt  = (const float*)d_in[20];

    char* ws = (char*)d_ws;
    size_t off = 0;
    auto alloc = [&](size_t bytes) {
        void* p = ws + off;
        off = (off + bytes + 255) & ~(size_t)255;
        return p;
    };
    float* Whz0   = (float*)alloc((size_t)NN*DD*sizeof(float));
    float* maxpre = (float*)alloc((size_t)2*BB*DD*sizeof(float));
    float* zlog   = (float*)alloc((size_t)2*BB*DD*sizeof(float));
    int*   ncnt   = (int*)alloc((size_t)2*BB*sizeof(int));
    int*   ncorr  = (int*)alloc((size_t)2*BB*sizeof(int));
    int2*  cpk    = (int2*)alloc((size_t)2*BB*MAXDEG*sizeof(int2));
    int*   zsrc   = (int*)alloc((size_t)2*BB*sizeof(int));
    int*   negsrc = (int*)alloc((size_t)BB*2*QQ*sizeof(int));
    int2*  npk    = (int2*)alloc((size_t)2*BB*MAXDEG*sizeof(int2));

    whz_init<<<NN/16, 512, 0, stream>>>(z0, Wh, bh, Whz0);
    nbr_kernel<<<2*BB, 256, 0, stream>>>(u, v, A, S, ncnt, npk);
    src_kernel<<<BB, 64, 0, stream>>>(u, v, neg, zsrc, negsrc);
    prep_kernel<<<2*BB, 128, 0, stream>>>(u, v, ncnt, npk, Whz0, maxpre, ncorr, cpk);
    scan_kernel<<<1, 512, 0, stream>>>(z0, td, ncnt, ncorr, cpk, maxpre, zsrc,
                                       Wh, bh, Wst, bst, Wrc, brc, Wt, bt, zlog);
    lam_kernel<<<BB*(1 + 2*QQ), 64, 0, stream>>>(z0, zlog, zsrc, negsrc, et,
                                                 w0, b0, w1, b1, psi, (float*)d_out);
}